// Round 1
// baseline (39509.570 us; speedup 1.0000x reference)
//
#include <hip/hip_runtime.h>
#include <math.h>

#define B_    32
#define NT    197     // tokens (196 patches + cls)
#define NP    196
#define D_    768
#define NH    12
#define HD_   64
#define MLP_  3072
#define QKVD  2304
#define NCLS  1000

// ---------------- patchify: x[B,3,224,224] -> tok[B*196, 768] ----------------
__global__ void patchify_k(const float* __restrict__ x, float* __restrict__ tok) {
    int bp = blockIdx.x;               // b*196 + p
    int b = bp / NP, p = bp % NP;
    int ph = p / 14, pw = p % 14;
    const float* xb = x + (size_t)b * 3 * 224 * 224;
    float* trow = tok + (size_t)bp * D_;
    for (int f = threadIdx.x; f < D_; f += blockDim.x) {
        int c = f >> 8;                // f = c*256 + i*16 + j
        int r = f & 255;
        int i = r >> 4, j = r & 15;
        trow[f] = xb[((size_t)c * 224 + (ph * 16 + i)) * 224 + (pw * 16 + j)];
    }
}

// --------------- assemble h: cls+pos row0, tokemb+pos rows 1..196 -------------
__global__ void assemble_h_k(const float* __restrict__ tokemb, const float* __restrict__ cls,
                             const float* __restrict__ pos, float* __restrict__ h) {
    int bn = blockIdx.x;               // b*197 + n
    int b = bn / NT, n = bn % NT;
    float* hr = h + (size_t)bn * D_;
    const float* pr = pos + (size_t)n * D_;
    if (n == 0) {
        for (int d = threadIdx.x; d < D_; d += blockDim.x) hr[d] = cls[d] + pr[d];
    } else {
        const float* tr = tokemb + ((size_t)b * NP + (n - 1)) * D_;
        for (int d = threadIdx.x; d < D_; d += blockDim.x) hr[d] = tr[d] + pr[d];
    }
}

// ---------------- LayerNorm over last dim (768) ------------------------------
// in rows addressed with in_row_stride (supports strided cls-row gather).
__global__ __launch_bounds__(256) void ln_k(const float* __restrict__ in, size_t in_row_stride,
                                            const float* __restrict__ w, const float* __restrict__ b,
                                            float* __restrict__ out) {
    int row = blockIdx.x;
    const float* xr = in + (size_t)row * in_row_stride;
    float* yr = out + (size_t)row * D_;
    int tid = threadIdx.x;
    float s1 = 0.f, s2 = 0.f;
    for (int d = tid; d < D_; d += 256) { float v = xr[d]; s1 += v; s2 += v * v; }
    #pragma unroll
    for (int off = 32; off; off >>= 1) { s1 += __shfl_down(s1, off); s2 += __shfl_down(s2, off); }
    __shared__ float r1[4], r2[4];
    int wave = tid >> 6, lane = tid & 63;
    if (lane == 0) { r1[wave] = s1; r2[wave] = s2; }
    __syncthreads();
    float m1 = (r1[0] + r1[1] + r1[2] + r1[3]) * (1.0f / D_);
    float m2 = (r2[0] + r2[1] + r2[2] + r2[3]) * (1.0f / D_);
    float rs = rsqrtf(m2 - m1 * m1 + 1e-5f);
    for (int d = tid; d < D_; d += 256)
        yr[d] = (xr[d] - m1) * rs * w[d] + b[d];
}

// ---------------- generic fp32 GEMM: C[M,N] = A[M,K] @ W[N,K]^T + bias -------
// EPI: 0 = store, 1 = C += result (residual), 2 = exact GELU
template<int EPI>
__global__ __launch_bounds__(256) void gemm_k(const float* __restrict__ A, const float* __restrict__ W,
                                              const float* __restrict__ bias, float* __restrict__ C,
                                              int M, int N, int K) {
    const int BM = 64, BN = 64, BK = 16;
    __shared__ float As[BK][BM + 1];
    __shared__ float Bs[BK][BN + 1];
    int bm = blockIdx.y * BM, bn = blockIdx.x * BN;
    int tid = threadIdx.x;             // 256 threads
    int tx = tid & 15, ty = tid >> 4;  // 16x16, each does 4x4
    float acc[4][4] = {};
    for (int k0 = 0; k0 < K; k0 += BK) {
        for (int l = tid; l < BM * BK; l += 256) {
            int row = l >> 4, kk = l & 15;
            int gr = bm + row;
            As[kk][row] = (gr < M) ? A[(size_t)gr * K + k0 + kk] : 0.f;
        }
        for (int l = tid; l < BN * BK; l += 256) {
            int col = l >> 4, kk = l & 15;
            int gc = bn + col;
            Bs[kk][col] = (gc < N) ? W[(size_t)gc * K + k0 + kk] : 0.f;
        }
        __syncthreads();
        #pragma unroll
        for (int kk = 0; kk < BK; ++kk) {
            float a0[4], b0[4];
            #pragma unroll
            for (int i = 0; i < 4; ++i) a0[i] = As[kk][ty * 4 + i];
            #pragma unroll
            for (int j = 0; j < 4; ++j) b0[j] = Bs[kk][tx * 4 + j];
            #pragma unroll
            for (int i = 0; i < 4; ++i)
                #pragma unroll
                for (int j = 0; j < 4; ++j) acc[i][j] += a0[i] * b0[j];
        }
        __syncthreads();
    }
    #pragma unroll
    for (int i = 0; i < 4; ++i) {
        int gr = bm + ty * 4 + i;
        if (gr >= M) continue;
        #pragma unroll
        for (int j = 0; j < 4; ++j) {
            int gc = bn + tx * 4 + j;
            if (gc >= N) continue;
            float v = acc[i][j] + (bias ? bias[gc] : 0.f);
            size_t idx = (size_t)gr * N + gc;
            if (EPI == 1)      C[idx] += v;
            else if (EPI == 2) C[idx] = 0.5f * v * (1.f + erff(v * 0.70710678118654752f));
            else               C[idx] = v;
        }
    }
}

// ---------------- attention: one block (128 thr) per (b, head, query n) ------
__global__ __launch_bounds__(128) void attn_k(const float* __restrict__ qkv, float* __restrict__ o,
                                              const float* __restrict__ alpha, const float* __restrict__ beta,
                                              const float* __restrict__ gamma, int layer, int poly) {
    int id = blockIdx.x;
    int n = id % NT;
    int bh = id / NT;
    int hh = bh % NH, b = bh / NH;
    __shared__ float qs[HD_];
    __shared__ float lg[NT];
    __shared__ float red[2];
    __shared__ float part[128];
    int tid = threadIdx.x;
    const float* base = qkv + (size_t)b * NT * QKVD;
    if (tid < HD_) qs[tid] = base[(size_t)n * QKVD + hh * HD_ + tid];
    __syncthreads();
    // logits
    for (int m = tid; m < NT; m += 128) {
        const float* kr = base + (size_t)m * QKVD + D_ + hh * HD_;
        float acc = 0.f;
        #pragma unroll
        for (int d = 0; d < HD_; ++d) acc += qs[d] * kr[d];
        lg[m] = acc * 0.125f;     // SCALE = 1/sqrt(64)
    }
    __syncthreads();
    if (poly) {
        float a = alpha[layer * NH + hh], bb = beta[layer * NH + hh], g = gamma[layer * NH + hh];
        float s = 0.f;
        for (int m = tid; m < NT; m += 128) {
            float l = lg[m];
            float p = fmaxf(a * l * l + bb * l + g, 0.f);
            lg[m] = p;
            s += p;
        }
        #pragma unroll
        for (int off = 32; off; off >>= 1) s += __shfl_down(s, off);
        if ((tid & 63) == 0) red[tid >> 6] = s;
        __syncthreads();
        float denom = red[0] + red[1] + 1e-6f;
        for (int m = tid; m < NT; m += 128) lg[m] /= denom;
    } else {
        float mx = -3.4e38f;
        for (int m = tid; m < NT; m += 128) mx = fmaxf(mx, lg[m]);
        #pragma unroll
        for (int off = 32; off; off >>= 1) mx = fmaxf(mx, __shfl_down(mx, off));
        if ((tid & 63) == 0) red[tid >> 6] = mx;
        __syncthreads();
        mx = fmaxf(red[0], red[1]);
        __syncthreads();
        float s = 0.f;
        for (int m = tid; m < NT; m += 128) { float e = expf(lg[m] - mx); lg[m] = e; s += e; }
        #pragma unroll
        for (int off = 32; off; off >>= 1) s += __shfl_down(s, off);
        if ((tid & 63) == 0) red[tid >> 6] = s;
        __syncthreads();
        float denom = red[0] + red[1];
        for (int m = tid; m < NT; m += 128) lg[m] /= denom;
    }
    __syncthreads();
    // o[n, d] = sum_m attn[m] * V[m, d]   (two partial sums over m)
    int d = tid & 63, half = tid >> 6;
    float acc = 0.f;
    const float* vb = base + 2 * D_ + hh * HD_ + d;
    for (int m = half; m < NT; m += 2) acc += lg[m] * vb[(size_t)m * QKVD];
    part[tid] = acc;
    __syncthreads();
    if (tid < HD_)
        o[((size_t)b * NT + n) * D_ + hh * HD_ + d] = part[tid] + part[tid + 64];
}

// -----------------------------------------------------------------------------
extern "C" void kernel_launch(void* const* d_in, const int* in_sizes, int n_in,
                              void* d_out, int out_size, void* d_ws, size_t ws_size,
                              hipStream_t stream) {
    (void)in_sizes; (void)n_in; (void)out_size; (void)ws_size;
    const float* x        = (const float*)d_in[0];
    const float* patch_w  = (const float*)d_in[1];
    const float* patch_b  = (const float*)d_in[2];
    const float* cls_tok  = (const float*)d_in[3];
    const float* pos      = (const float*)d_in[4];
    const float* ln1_w    = (const float*)d_in[5];
    const float* ln1_b    = (const float*)d_in[6];
    const float* qkv_w    = (const float*)d_in[7];
    const float* proj_w   = (const float*)d_in[8];
    const float* proj_b   = (const float*)d_in[9];
    const float* ln2_w    = (const float*)d_in[10];
    const float* ln2_b    = (const float*)d_in[11];
    const float* mlp_w1   = (const float*)d_in[12];
    const float* mlp_b1   = (const float*)d_in[13];
    const float* mlp_w2   = (const float*)d_in[14];
    const float* mlp_b2   = (const float*)d_in[15];
    const float* alpha    = (const float*)d_in[16];
    const float* beta     = (const float*)d_in[17];
    const float* gamma    = (const float*)d_in[18];
    const float* norm_w   = (const float*)d_in[19];
    const float* norm_b   = (const float*)d_in[20];
    const float* head_w   = (const float*)d_in[21];
    const float* head_b   = (const float*)d_in[22];

    const int MASK[12] = {1,0,1,0,1,0,1,0,1,0,1,0};
    const size_t ROWS = (size_t)B_ * NT;   // 6304

    float* ws   = (float*)d_ws;
    float* h    = ws;                       // 6304*768
    float* tmp1 = h    + ROWS * D_;         // 6304*768  (ln out / attn out)
    float* qkvb = tmp1 + ROWS * D_;         // 6304*2304
    float* tmp2 = qkvb + ROWS * QKVD;       // 6304*3072 (mlp hidden; also tok + tokemb)
    float* tok    = tmp2;                   // 6272*768
    float* tokemb = tmp2 + (size_t)B_ * NP * D_;  // 6272*768 (fits in tmp2's 19.3M floats)

    // ---- patch embedding ----
    patchify_k<<<B_ * NP, 256, 0, stream>>>(x, tok);
    {
        dim3 g((D_ + 63) / 64, (B_ * NP + 63) / 64);
        gemm_k<0><<<g, 256, 0, stream>>>(tok, patch_w, patch_b, tokemb, B_ * NP, D_, D_);
    }
    assemble_h_k<<<B_ * NT, 256, 0, stream>>>(tokemb, cls_tok, pos, h);

    // ---- transformer layers ----
    for (int i = 0; i < 12; ++i) {
        ln_k<<<(int)ROWS, 256, 0, stream>>>(h, D_, ln1_w + (size_t)i * D_, ln1_b + (size_t)i * D_, tmp1);
        {
            dim3 g(QKVD / 64, ((int)ROWS + 63) / 64);
            gemm_k<0><<<g, 256, 0, stream>>>(tmp1, qkv_w + (size_t)i * QKVD * D_, nullptr, qkvb,
                                             (int)ROWS, QKVD, D_);
        }
        attn_k<<<B_ * NH * NT, 128, 0, stream>>>(qkvb, tmp1, alpha, beta, gamma, i, MASK[i]);
        {
            dim3 g(D_ / 64, ((int)ROWS + 63) / 64);
            gemm_k<1><<<g, 256, 0, stream>>>(tmp1, proj_w + (size_t)i * D_ * D_, proj_b + (size_t)i * D_,
                                             h, (int)ROWS, D_, D_);
        }
        ln_k<<<(int)ROWS, 256, 0, stream>>>(h, D_, ln2_w + (size_t)i * D_, ln2_b + (size_t)i * D_, tmp1);
        {
            dim3 g(MLP_ / 64, ((int)ROWS + 63) / 64);
            gemm_k<2><<<g, 256, 0, stream>>>(tmp1, mlp_w1 + (size_t)i * MLP_ * D_, mlp_b1 + (size_t)i * MLP_,
                                             tmp2, (int)ROWS, MLP_, D_);
        }
        {
            dim3 g(D_ / 64, ((int)ROWS + 63) / 64);
            gemm_k<1><<<g, 256, 0, stream>>>(tmp2, mlp_w2 + (size_t)i * D_ * MLP_, mlp_b2 + (size_t)i * D_,
                                             h, (int)ROWS, D_, MLP_);
        }
    }

    // ---- head: LN(cls rows) then [32,768] @ [1000,768]^T + bias ----
    ln_k<<<B_, 256, 0, stream>>>(h, (size_t)NT * D_, norm_w, norm_b, tmp1);
    {
        dim3 g((NCLS + 63) / 64, 1);
        gemm_k<0><<<g, 256, 0, stream>>>(tmp1, head_w, head_b, (float*)d_out, B_, NCLS, D_);
    }
}

// Round 2
// 6787.833 us; speedup vs baseline: 5.8206x; 5.8206x over previous
//
#include <hip/hip_runtime.h>
#include <math.h>

#define B_    32
#define NT    197     // tokens (196 patches + cls)
#define NP    196
#define D_    768
#define NH    12
#define HD_   64
#define MLP_  3072
#define QKVD  2304
#define NCLS  1000

typedef unsigned short u16;
typedef __bf16 bf16x8 __attribute__((ext_vector_type(8)));
typedef float  f32x4  __attribute__((ext_vector_type(4)));
struct alignas(8) u16x4_t { u16 x, y, z, w; };

__device__ __forceinline__ u16 f2bf(float f) {
    unsigned u = __builtin_bit_cast(unsigned, f);
    u = u + 0x7FFFu + ((u >> 16) & 1u);
    return (u16)(u >> 16);
}
__device__ __forceinline__ float bf2f(u16 s) {
    return __builtin_bit_cast(float, ((unsigned)s) << 16);
}
__device__ __forceinline__ void gload_lds16(const void* g, void* l) {
    __builtin_amdgcn_global_load_lds((const __attribute__((address_space(1))) unsigned*)g,
                                     (__attribute__((address_space(3))) unsigned*)l, 16, 0, 0);
}

// ---------------- patchify: x[B,3,224,224] -> tok bf16 [B*196, 768] ----------
__global__ void patchify_k(const float* __restrict__ x, u16* __restrict__ tok) {
    int bp = blockIdx.x;
    int b = bp / NP, p = bp % NP;
    int ph = p / 14, pw = p % 14;
    const float* xb = x + (size_t)b * 3 * 224 * 224;
    u16* trow = tok + (size_t)bp * D_;
    for (int f = threadIdx.x; f < D_; f += blockDim.x) {
        int c = f >> 8;
        int r = f & 255;
        int i = r >> 4, j = r & 15;
        trow[f] = f2bf(xb[((size_t)c * 224 + (ph * 16 + i)) * 224 + (pw * 16 + j)]);
    }
}

// --------------- assemble h (fp32): cls+pos row0, tokemb+pos rows 1..196 -----
__global__ void assemble_h_k(const float* __restrict__ tokemb, const float* __restrict__ cls,
                             const float* __restrict__ pos, float* __restrict__ h) {
    int bn = blockIdx.x;
    int b = bn / NT, n = bn % NT;
    float* hr = h + (size_t)bn * D_;
    const float* pr = pos + (size_t)n * D_;
    if (n == 0) {
        for (int d = threadIdx.x; d < D_; d += blockDim.x) hr[d] = cls[d] + pr[d];
    } else {
        const float* tr = tokemb + ((size_t)b * NP + (n - 1)) * D_;
        for (int d = threadIdx.x; d < D_; d += blockDim.x) hr[d] = tr[d] + pr[d];
    }
}

// ---------------- fp32 -> bf16 weight conversion -----------------------------
__global__ void cvt1_k(const float* __restrict__ src, u16* __restrict__ dst, int n4) {
    int i = (blockIdx.x * 256 + threadIdx.x) * 4;
    if (i >= n4) return;
    float4 v = *(const float4*)(src + i);
    u16x4_t o; o.x = f2bf(v.x); o.y = f2bf(v.y); o.z = f2bf(v.z); o.w = f2bf(v.w);
    *(u16x4_t*)(dst + i) = o;
}

// fused per-layer weight conversion into wbuf [qkv | proj | mlp1 | mlp2]
__global__ void cvtw_k(const float* __restrict__ qw, const float* __restrict__ pw,
                       const float* __restrict__ m1, const float* __restrict__ m2,
                       u16* __restrict__ dst) {
    const size_t n0 = 1769472, n1 = 2359296, n2 = 4718592, n3 = 7077888;
    size_t e = ((size_t)blockIdx.x * 256 + threadIdx.x) * 4;
    if (e >= n3) return;
    const float* src; size_t off;
    if (e < n0)      { src = qw; off = e; }
    else if (e < n1) { src = pw; off = e - n0; }
    else if (e < n2) { src = m1; off = e - n1; }
    else             { src = m2; off = e - n2; }
    float4 v = *(const float4*)(src + off);
    u16x4_t o; o.x = f2bf(v.x); o.y = f2bf(v.y); o.z = f2bf(v.z); o.w = f2bf(v.w);
    *(u16x4_t*)(dst + e) = o;
}

// ---------------- LayerNorm over last dim (768), fp32 in, fp32/bf16 out ------
template<int OUTBF>
__global__ __launch_bounds__(256) void ln_k(const float* __restrict__ in, size_t in_row_stride,
                                            const float* __restrict__ w, const float* __restrict__ b,
                                            float* __restrict__ of, u16* __restrict__ ob) {
    int row = blockIdx.x;
    const float* xr = in + (size_t)row * in_row_stride;
    int tid = threadIdx.x;
    float s1 = 0.f, s2 = 0.f;
    for (int d = tid; d < D_; d += 256) { float v = xr[d]; s1 += v; s2 += v * v; }
    #pragma unroll
    for (int off = 32; off; off >>= 1) { s1 += __shfl_down(s1, off); s2 += __shfl_down(s2, off); }
    __shared__ float r1[4], r2[4];
    int wave = tid >> 6, lane = tid & 63;
    if (lane == 0) { r1[wave] = s1; r2[wave] = s2; }
    __syncthreads();
    float m1 = (r1[0] + r1[1] + r1[2] + r1[3]) * (1.0f / D_);
    float m2 = (r2[0] + r2[1] + r2[2] + r2[3]) * (1.0f / D_);
    float rs = rsqrtf(m2 - m1 * m1 + 1e-5f);
    for (int d = tid; d < D_; d += 256) {
        float y = (xr[d] - m1) * rs * w[d] + b[d];
        if (OUTBF) ob[(size_t)row * D_ + d] = f2bf(y);
        else       of[(size_t)row * D_ + d] = y;
    }
}

// ---------------- bf16 MFMA GEMM: C[M,N] = A[M,K] @ W[N,K]^T (+bias) ---------
// 128x128 tile, BK=64, 256 thr = 4 waves in 2x2, each wave 4x4 16x16x32 MFMAs.
// EPI: 0 = store fp32, 1 = fp32 += (residual), 2 = GELU -> bf16 store
template<int EPI>
__global__ __launch_bounds__(256) void mgemm_k(const u16* __restrict__ A, const u16* __restrict__ W,
                                               const float* __restrict__ bias, float* __restrict__ Cf,
                                               u16* __restrict__ Cb, int M, int N, int K) {
    __shared__ u16 As[128 * 64];
    __shared__ u16 Ws[128 * 64];
    const int tid = threadIdx.x;
    const int lane = tid & 63, wv = tid >> 6;
    const int wr = wv >> 1, wc = wv & 1;
    const int bm = blockIdx.y * 128, bn = blockIdx.x * 128;
    const int arow = tid >> 3;          // 0..31
    const int acol = (tid & 7) * 8;     // bf16 col within BK=64
    const int l15 = lane & 15, quad = lane >> 4;
    f32x4 acc[4][4] = {};
    for (int k0 = 0; k0 < K; k0 += 64) {
        #pragma unroll
        for (int q = 0; q < 4; ++q) {
            int gr = bm + q * 32 + arow;
            if (gr > M - 1) gr = M - 1;                       // clamp edge tile
            gload_lds16(A + (size_t)gr * K + k0 + acol, (char*)As + q * 4096 + tid * 16);
        }
        #pragma unroll
        for (int q = 0; q < 4; ++q) {
            int r = q * 32 + arow;                            // N is always a multiple of 128
            gload_lds16(W + (size_t)(bn + r) * K + k0 + acol, (char*)Ws + q * 4096 + tid * 16);
        }
        __syncthreads();
        #pragma unroll
        for (int kk = 0; kk < 64; kk += 32) {
            bf16x8 af[4], bfr[4];
            #pragma unroll
            for (int i = 0; i < 4; ++i)
                af[i] = *(const bf16x8*)(As + (wr * 64 + i * 16 + l15) * 64 + kk + quad * 8);
            #pragma unroll
            for (int j = 0; j < 4; ++j)
                bfr[j] = *(const bf16x8*)(Ws + (wc * 64 + j * 16 + l15) * 64 + kk + quad * 8);
            #pragma unroll
            for (int i = 0; i < 4; ++i)
                #pragma unroll
                for (int j = 0; j < 4; ++j)
                    acc[i][j] = __builtin_amdgcn_mfma_f32_16x16x32_bf16(af[i], bfr[j], acc[i][j], 0, 0, 0);
        }
        __syncthreads();
    }
    #pragma unroll
    for (int i = 0; i < 4; ++i) {
        int rb = bm + wr * 64 + i * 16 + quad * 4;            // C/D: col=lane&15, row=quad*4+reg
        #pragma unroll
        for (int j = 0; j < 4; ++j) {
            int gc = bn + wc * 64 + j * 16 + l15;
            #pragma unroll
            for (int r = 0; r < 4; ++r) {
                int gr = rb + r;
                if (gr >= M) continue;
                float v = acc[i][j][r];
                if (bias) v += bias[gc];
                size_t idx = (size_t)gr * N + gc;
                if (EPI == 0)      Cf[idx] = v;
                else if (EPI == 1) Cf[idx] += v;
                else Cb[idx] = f2bf(0.5f * v * (1.f + erff(v * 0.70710678118654752f)));
            }
        }
    }
}

// ---------------- fp32 GEMM (head only): C[M,N] = A@W^T + bias ---------------
__global__ __launch_bounds__(256) void sgemm_k(const float* __restrict__ A, const float* __restrict__ W,
                                               const float* __restrict__ bias, float* __restrict__ C,
                                               int M, int N, int K) {
    const int BM = 64, BN = 64, BK = 16;
    __shared__ float Asm[BK][BM + 1];
    __shared__ float Bsm[BK][BN + 1];
    int bm = blockIdx.y * BM, bn = blockIdx.x * BN;
    int tid = threadIdx.x;
    int tx = tid & 15, ty = tid >> 4;
    float acc[4][4] = {};
    for (int k0 = 0; k0 < K; k0 += BK) {
        for (int l = tid; l < BM * BK; l += 256) {
            int row = l >> 4, kk = l & 15;
            int gr = bm + row;
            Asm[kk][row] = (gr < M) ? A[(size_t)gr * K + k0 + kk] : 0.f;
        }
        for (int l = tid; l < BN * BK; l += 256) {
            int col = l >> 4, kk = l & 15;
            int gc = bn + col;
            Bsm[kk][col] = (gc < N) ? W[(size_t)gc * K + k0 + kk] : 0.f;
        }
        __syncthreads();
        #pragma unroll
        for (int kk = 0; kk < BK; ++kk) {
            float a0[4], b0[4];
            #pragma unroll
            for (int i = 0; i < 4; ++i) a0[i] = Asm[kk][ty * 4 + i];
            #pragma unroll
            for (int j = 0; j < 4; ++j) b0[j] = Bsm[kk][tx * 4 + j];
            #pragma unroll
            for (int i = 0; i < 4; ++i)
                #pragma unroll
                for (int j = 0; j < 4; ++j) acc[i][j] += a0[i] * b0[j];
        }
        __syncthreads();
    }
    #pragma unroll
    for (int i = 0; i < 4; ++i) {
        int gr = bm + ty * 4 + i;
        if (gr >= M) continue;
        #pragma unroll
        for (int j = 0; j < 4; ++j) {
            int gc = bn + tx * 4 + j;
            if (gc >= N) continue;
            C[(size_t)gr * N + gc] = acc[i][j] + (bias ? bias[gc] : 0.f);
        }
    }
}

// ---------------- attention: one block per (b, head, half) -------------------
// K bf16 LDS row-major [197][68], V bf16 LDS transposed [64][204].
__global__ __launch_bounds__(256) void attn_k(const float* __restrict__ qkv, u16* __restrict__ o,
                                              const float* __restrict__ alpha, const float* __restrict__ beta,
                                              const float* __restrict__ gamma, int layer, int poly) {
    __shared__ u16 Kb[197 * 68];
    __shared__ u16 Vt[64 * 204];
    __shared__ float qsh[4][64];
    __shared__ float psh[4][224];
    int tid = threadIdx.x, wv = tid >> 6, lane = tid & 63;
    int id = blockIdx.x;
    int half = id & 1, bh = id >> 1;
    int hh = bh % NH, b = bh / NH;
    const float* base = qkv + (size_t)b * NT * QKVD;
    // stage K (row-major) and V (transposed)
    for (int idx = tid; idx < NT * 64; idx += 256) {
        int m = idx >> 6, d = idx & 63;
        Kb[m * 68 + d]  = f2bf(base[(size_t)m * QKVD + D_     + hh * 64 + d]);
        Vt[d * 204 + m] = f2bf(base[(size_t)m * QKVD + 2 * D_ + hh * 64 + d]);
    }
    for (int idx = tid; idx < 64 * 7; idx += 256) {   // zero V tail cols 197..203
        int d = idx / 7, c = idx % 7;
        Vt[d * 204 + 197 + c] = 0;
    }
    __syncthreads();
    float pa = 0.f, pb = 0.f, pg = 0.f;
    if (poly) { pa = alpha[layer * NH + hh]; pb = beta[layer * NH + hh]; pg = gamma[layer * NH + hh]; }

    for (int n = wv + 4 * half; n < NT; n += 8) {
        qsh[wv][lane] = base[(size_t)n * QKVD + hh * 64 + lane];
        // logits: lane handles m = lane, lane+64, lane+128 (always valid), 192+lane (lane<5)
        float l0 = 0.f, l1 = 0.f, l2 = 0.f, l3 = 0.f;
        int m3 = 192 + lane; if (m3 > 196) m3 = 196;
        for (int d2 = 0; d2 < 32; ++d2) {
            float2 qq = *(const float2*)&qsh[wv][2 * d2];
            unsigned k0 = *(const unsigned*)&Kb[(lane)       * 68 + 2 * d2];
            unsigned k1 = *(const unsigned*)&Kb[(lane + 64)  * 68 + 2 * d2];
            unsigned k2 = *(const unsigned*)&Kb[(lane + 128) * 68 + 2 * d2];
            unsigned k3 = *(const unsigned*)&Kb[(m3)         * 68 + 2 * d2];
            l0 += qq.x * __builtin_bit_cast(float, k0 << 16) + qq.y * __builtin_bit_cast(float, k0 & 0xFFFF0000u);
            l1 += qq.x * __builtin_bit_cast(float, k1 << 16) + qq.y * __builtin_bit_cast(float, k1 & 0xFFFF0000u);
            l2 += qq.x * __builtin_bit_cast(float, k2 << 16) + qq.y * __builtin_bit_cast(float, k2 & 0xFFFF0000u);
            l3 += qq.x * __builtin_bit_cast(float, k3 << 16) + qq.y * __builtin_bit_cast(float, k3 & 0xFFFF0000u);
        }
        l0 *= 0.125f; l1 *= 0.125f; l2 *= 0.125f; l3 *= 0.125f;
        bool v3 = (lane < 5);
        float inv;
        if (poly) {
            float p0 = fmaxf(pa * l0 * l0 + pb * l0 + pg, 0.f);
            float p1 = fmaxf(pa * l1 * l1 + pb * l1 + pg, 0.f);
            float p2 = fmaxf(pa * l2 * l2 + pb * l2 + pg, 0.f);
            float p3 = v3 ? fmaxf(pa * l3 * l3 + pb * l3 + pg, 0.f) : 0.f;
            float s = p0 + p1 + p2 + p3;
            #pragma unroll
            for (int off = 32; off; off >>= 1) s += __shfl_xor(s, off);
            inv = 1.f / (s + 1e-6f);
            psh[wv][lane] = p0; psh[wv][lane + 64] = p1; psh[wv][lane + 128] = p2;
            if (v3) psh[wv][192 + lane] = p3;
        } else {
            float mx = fmaxf(fmaxf(l0, l1), l2);
            if (v3) mx = fmaxf(mx, l3);
            #pragma unroll
            for (int off = 32; off; off >>= 1) mx = fmaxf(mx, __shfl_xor(mx, off));
            float e0 = expf(l0 - mx), e1 = expf(l1 - mx), e2 = expf(l2 - mx);
            float e3 = v3 ? expf(l3 - mx) : 0.f;
            float s = e0 + e1 + e2 + e3;
            #pragma unroll
            for (int off = 32; off; off >>= 1) s += __shfl_xor(s, off);
            inv = 1.f / s;
            psh[wv][lane] = e0; psh[wv][lane + 64] = e1; psh[wv][lane + 128] = e2;
            if (v3) psh[wv][192 + lane] = e3;
        }
        if (lane < 3) psh[wv][197 + lane] = 0.f;
        // o[d=lane] = sum_m p[m] * V[m][d]
        float accf = 0.f;
        const u16* vrow = &Vt[lane * 204];
        for (int m4 = 0; m4 < 200; m4 += 4) {
            float4 p = *(const float4*)&psh[wv][m4];
            u16x4_t vvv = *(const u16x4_t*)&vrow[m4];
            accf += p.x * bf2f(vvv.x) + p.y * bf2f(vvv.y) + p.z * bf2f(vvv.z) + p.w * bf2f(vvv.w);
        }
        o[((size_t)b * NT + n) * D_ + hh * 64 + lane] = f2bf(accf * inv);
    }
}

// -----------------------------------------------------------------------------
extern "C" void kernel_launch(void* const* d_in, const int* in_sizes, int n_in,
                              void* d_out, int out_size, void* d_ws, size_t ws_size,
                              hipStream_t stream) {
    (void)in_sizes; (void)n_in; (void)out_size; (void)ws_size;
    const float* x        = (const float*)d_in[0];
    const float* patch_w  = (const float*)d_in[1];
    const float* patch_b  = (const float*)d_in[2];
    const float* cls_tok  = (const float*)d_in[3];
    const float* pos      = (const float*)d_in[4];
    const float* ln1_w    = (const float*)d_in[5];
    const float* ln1_b    = (const float*)d_in[6];
    const float* qkv_w    = (const float*)d_in[7];
    const float* proj_w   = (const float*)d_in[8];
    const float* proj_b   = (const float*)d_in[9];
    const float* ln2_w    = (const float*)d_in[10];
    const float* ln2_b    = (const float*)d_in[11];
    const float* mlp_w1   = (const float*)d_in[12];
    const float* mlp_b1   = (const float*)d_in[13];
    const float* mlp_w2   = (const float*)d_in[14];
    const float* mlp_b2   = (const float*)d_in[15];
    const float* alpha    = (const float*)d_in[16];
    const float* beta     = (const float*)d_in[17];
    const float* gamma    = (const float*)d_in[18];
    const float* norm_w   = (const float*)d_in[19];
    const float* norm_b   = (const float*)d_in[20];
    const float* head_w   = (const float*)d_in[21];
    const float* head_b   = (const float*)d_in[22];

    const int MASK[12] = {1,0,1,0,1,0,1,0,1,0,1,0};
    const size_t ROWS = (size_t)B_ * NT;   // 6304

    char* p = (char*)d_ws;
    float* h    = (float*)p;  p += ROWS * D_ * 4;          // 19.4 MB
    float* qkvb = (float*)p;  p += ROWS * QKVD * 4;        // 58.1 MB (also tokemb)
    u16*   abuf = (u16*)p;    p += ROWS * D_ * 2;          // 9.7 MB  (ln/attn outs)
    u16*   gbuf = (u16*)p;    p += ROWS * MLP_ * 2;        // 38.7 MB (gelu out; also tok)
    u16*   wbuf = (u16*)p;    p += (size_t)7077888 * 2;    // 14.2 MB (per-layer bf16 weights)
    float* hb   = (float*)p;  p += 32 * D_ * 4;

    u16* wq = wbuf;
    u16* wp = wq + 1769472;
    u16* w1 = wp + 589824;
    u16* w2 = w1 + 2359296;

    // ---- patch embedding (bf16 MFMA) ----
    cvt1_k<<<576, 256, 0, stream>>>(patch_w, wbuf, 589824);
    patchify_k<<<B_ * NP, 256, 0, stream>>>(x, gbuf);
    mgemm_k<0><<<dim3(D_ / 128, 49), 256, 0, stream>>>(gbuf, wbuf, patch_b, qkvb, nullptr,
                                                       B_ * NP, D_, D_);
    assemble_h_k<<<B_ * NT, 256, 0, stream>>>(qkvb, cls_tok, pos, h);

    // ---- transformer layers ----
    for (int i = 0; i < 12; ++i) {
        cvtw_k<<<6912, 256, 0, stream>>>(qkv_w + (size_t)i * 1769472, proj_w + (size_t)i * 589824,
                                         mlp_w1 + (size_t)i * 2359296, mlp_w2 + (size_t)i * 2359296, wbuf);
        ln_k<1><<<(int)ROWS, 256, 0, stream>>>(h, D_, ln1_w + (size_t)i * D_, ln1_b + (size_t)i * D_,
                                               nullptr, abuf);
        mgemm_k<0><<<dim3(QKVD / 128, 50), 256, 0, stream>>>(abuf, wq, nullptr, qkvb, nullptr,
                                                             (int)ROWS, QKVD, D_);
        attn_k<<<B_ * NH * 2, 256, 0, stream>>>(qkvb, abuf, alpha, beta, gamma, i, MASK[i]);
        mgemm_k<1><<<dim3(D_ / 128, 50), 256, 0, stream>>>(abuf, wp, proj_b + (size_t)i * D_, h, nullptr,
                                                           (int)ROWS, D_, D_);
        ln_k<1><<<(int)ROWS, 256, 0, stream>>>(h, D_, ln2_w + (size_t)i * D_, ln2_b + (size_t)i * D_,
                                               nullptr, abuf);
        mgemm_k<2><<<dim3(MLP_ / 128, 50), 256, 0, stream>>>(abuf, w1, mlp_b1 + (size_t)i * MLP_,
                                                             nullptr, gbuf, (int)ROWS, MLP_, D_);
        mgemm_k<1><<<dim3(D_ / 128, 50), 256, 0, stream>>>(gbuf, w2, mlp_b2 + (size_t)i * D_, h, nullptr,
                                                           (int)ROWS, D_, MLP_);
    }

    // ---- head: LN(cls rows) fp32, then [32,768] @ [1000,768]^T + bias -------
    ln_k<0><<<B_, 256, 0, stream>>>(h, (size_t)NT * D_, norm_w, norm_b, hb, nullptr);
    sgemm_k<<<dim3((NCLS + 63) / 64, 1), 256, 0, stream>>>(hb, head_w, head_b, (float*)d_out,
                                                           B_, NCLS, D_);
}

// Round 3
// 5407.999 us; speedup vs baseline: 7.3058x; 1.2551x over previous
//
#include <hip/hip_runtime.h>
#include <math.h>

#define B_    32
#define NT    197     // tokens (196 patches + cls)
#define NP    196
#define D_    768
#define NH    12
#define HD_   64
#define MLP_  3072
#define QKVD  2304
#define NCLS  1000

typedef unsigned short u16;
typedef __bf16 bf16x8 __attribute__((ext_vector_type(8)));
typedef float  f32x4  __attribute__((ext_vector_type(4)));
struct alignas(8) u16x4_t { u16 x, y, z, w; };

__device__ __forceinline__ u16 f2bf(float f) {
    unsigned u = __builtin_bit_cast(unsigned, f);
    u = u + 0x7FFFu + ((u >> 16) & 1u);
    return (u16)(u >> 16);
}
__device__ __forceinline__ void gload_lds16(const void* g, void* l) {
    __builtin_amdgcn_global_load_lds((const __attribute__((address_space(1))) unsigned*)g,
                                     (__attribute__((address_space(3))) unsigned*)l, 16, 0, 0);
}

// ---------------- patchify: x[B,3,224,224] -> tok bf16 [B*196, 768] ----------
__global__ void patchify_k(const float* __restrict__ x, u16* __restrict__ tok) {
    int bp = blockIdx.x;
    int b = bp / NP, p = bp % NP;
    int ph = p / 14, pw = p % 14;
    const float* xb = x + (size_t)b * 3 * 224 * 224;
    u16* trow = tok + (size_t)bp * D_;
    for (int f = threadIdx.x; f < D_; f += blockDim.x) {
        int c = f >> 8;
        int r = f & 255;
        int i = r >> 4, j = r & 15;
        trow[f] = f2bf(xb[((size_t)c * 224 + (ph * 16 + i)) * 224 + (pw * 16 + j)]);
    }
}

// --------------- assemble h (fp32): cls+pos row0, tokemb+pos rows 1..196 -----
__global__ void assemble_h_k(const float* __restrict__ tokemb, const float* __restrict__ cls,
                             const float* __restrict__ pos, float* __restrict__ h) {
    int bn = blockIdx.x;
    int b = bn / NT, n = bn % NT;
    float* hr = h + (size_t)bn * D_;
    const float* pr = pos + (size_t)n * D_;
    if (n == 0) {
        for (int d = threadIdx.x; d < D_; d += blockDim.x) hr[d] = cls[d] + pr[d];
    } else {
        const float* tr = tokemb + ((size_t)b * NP + (n - 1)) * D_;
        for (int d = threadIdx.x; d < D_; d += blockDim.x) hr[d] = tr[d] + pr[d];
    }
}

// ---------------- fp32 -> bf16 weight conversion -----------------------------
__global__ void cvt1_k(const float* __restrict__ src, u16* __restrict__ dst, int n4) {
    int i = (blockIdx.x * 256 + threadIdx.x) * 4;
    if (i >= n4) return;
    float4 v = *(const float4*)(src + i);
    u16x4_t o; o.x = f2bf(v.x); o.y = f2bf(v.y); o.z = f2bf(v.z); o.w = f2bf(v.w);
    *(u16x4_t*)(dst + i) = o;
}

// fused per-layer weight conversion into wbuf [qkv | proj | mlp1 | mlp2]
__global__ void cvtw_k(const float* __restrict__ qw, const float* __restrict__ pw,
                       const float* __restrict__ m1, const float* __restrict__ m2,
                       u16* __restrict__ dst) {
    const size_t n0 = 1769472, n1 = 2359296, n2 = 4718592, n3 = 7077888;
    size_t e = ((size_t)blockIdx.x * 256 + threadIdx.x) * 4;
    if (e >= n3) return;
    const float* src; size_t off;
    if (e < n0)      { src = qw; off = e; }
    else if (e < n1) { src = pw; off = e - n0; }
    else if (e < n2) { src = m1; off = e - n1; }
    else             { src = m2; off = e - n2; }
    float4 v = *(const float4*)(src + off);
    u16x4_t o; o.x = f2bf(v.x); o.y = f2bf(v.y); o.z = f2bf(v.z); o.w = f2bf(v.w);
    *(u16x4_t*)(dst + e) = o;
}

// ---------------- LayerNorm over last dim (768), fp32 in, fp32/bf16 out ------
template<int OUTBF>
__global__ __launch_bounds__(256) void ln_k(const float* __restrict__ in, size_t in_row_stride,
                                            const float* __restrict__ w, const float* __restrict__ b,
                                            float* __restrict__ of, u16* __restrict__ ob) {
    int row = blockIdx.x;
    const float* xr = in + (size_t)row * in_row_stride;
    int tid = threadIdx.x;
    float s1 = 0.f, s2 = 0.f;
    for (int d = tid; d < D_; d += 256) { float v = xr[d]; s1 += v; s2 += v * v; }
    #pragma unroll
    for (int off = 32; off; off >>= 1) { s1 += __shfl_down(s1, off); s2 += __shfl_down(s2, off); }
    __shared__ float r1[4], r2[4];
    int wave = tid >> 6, lane = tid & 63;
    if (lane == 0) { r1[wave] = s1; r2[wave] = s2; }
    __syncthreads();
    float m1 = (r1[0] + r1[1] + r1[2] + r1[3]) * (1.0f / D_);
    float m2 = (r2[0] + r2[1] + r2[2] + r2[3]) * (1.0f / D_);
    float rs = rsqrtf(m2 - m1 * m1 + 1e-5f);
    for (int d = tid; d < D_; d += 256) {
        float y = (xr[d] - m1) * rs * w[d] + b[d];
        if (OUTBF) ob[(size_t)row * D_ + d] = f2bf(y);
        else       of[(size_t)row * D_ + d] = y;
    }
}

// ---------------- bf16 MFMA GEMM: C[M,N] = A[M,K] @ W[N,K]^T (+bias) ---------
// 128x128 tile, BK=64, 256 thr = 4 waves in 2x2, each wave 4x4 16x16x32 MFMAs.
// EPI: 0 = store fp32, 1 = fp32 += (residual), 2 = GELU -> bf16, 3 = bf16 store
template<int EPI>
__global__ __launch_bounds__(256) void mgemm_k(const u16* __restrict__ A, const u16* __restrict__ W,
                                               const float* __restrict__ bias, float* __restrict__ Cf,
                                               u16* __restrict__ Cb, int M, int N, int K) {
    __shared__ u16 As[128 * 64];
    __shared__ u16 Ws[128 * 64];
    const int tid = threadIdx.x;
    const int lane = tid & 63, wv = tid >> 6;
    const int wr = wv >> 1, wc = wv & 1;
    const int bm = blockIdx.y * 128, bn = blockIdx.x * 128;
    const int arow = tid >> 3;          // 0..31
    const int acol = (tid & 7) * 8;     // bf16 col within BK=64
    const int l15 = lane & 15, quad = lane >> 4;
    f32x4 acc[4][4] = {};
    for (int k0 = 0; k0 < K; k0 += 64) {
        #pragma unroll
        for (int q = 0; q < 4; ++q) {
            int gr = bm + q * 32 + arow;
            if (gr > M - 1) gr = M - 1;                       // clamp edge tile
            gload_lds16(A + (size_t)gr * K + k0 + acol, (char*)As + q * 4096 + tid * 16);
        }
        #pragma unroll
        for (int q = 0; q < 4; ++q) {
            int r = q * 32 + arow;                            // N is always a multiple of 128
            gload_lds16(W + (size_t)(bn + r) * K + k0 + acol, (char*)Ws + q * 4096 + tid * 16);
        }
        __syncthreads();
        #pragma unroll
        for (int kk = 0; kk < 64; kk += 32) {
            bf16x8 af[4], bfr[4];
            #pragma unroll
            for (int i = 0; i < 4; ++i)
                af[i] = *(const bf16x8*)(As + (wr * 64 + i * 16 + l15) * 64 + kk + quad * 8);
            #pragma unroll
            for (int j = 0; j < 4; ++j)
                bfr[j] = *(const bf16x8*)(Ws + (wc * 64 + j * 16 + l15) * 64 + kk + quad * 8);
            #pragma unroll
            for (int i = 0; i < 4; ++i)
                #pragma unroll
                for (int j = 0; j < 4; ++j)
                    acc[i][j] = __builtin_amdgcn_mfma_f32_16x16x32_bf16(af[i], bfr[j], acc[i][j], 0, 0, 0);
        }
        __syncthreads();
    }
    #pragma unroll
    for (int i = 0; i < 4; ++i) {
        int rb = bm + wr * 64 + i * 16 + quad * 4;            // C/D: col=lane&15, row=quad*4+reg
        #pragma unroll
        for (int j = 0; j < 4; ++j) {
            int gc = bn + wc * 64 + j * 16 + l15;
            #pragma unroll
            for (int r = 0; r < 4; ++r) {
                int gr = rb + r;
                if (gr >= M) continue;
                float v = acc[i][j][r];
                if (bias) v += bias[gc];
                size_t idx = (size_t)gr * N + gc;
                if (EPI == 0)      Cf[idx] = v;
                else if (EPI == 1) Cf[idx] += v;
                else if (EPI == 3) Cb[idx] = f2bf(v);
                else Cb[idx] = f2bf(0.5f * v * (1.f + erff(v * 0.70710678118654752f)));
            }
        }
    }
}

// ---------------- fp32 GEMM (head only): C[M,N] = A@W^T + bias ---------------
__global__ __launch_bounds__(256) void sgemm_k(const float* __restrict__ A, const float* __restrict__ W,
                                               const float* __restrict__ bias, float* __restrict__ C,
                                               int M, int N, int K) {
    const int BM = 64, BN = 64, BK = 16;
    __shared__ float Asm[BK][BM + 1];
    __shared__ float Bsm[BK][BN + 1];
    int bm = blockIdx.y * BM, bn = blockIdx.x * BN;
    int tid = threadIdx.x;
    int tx = tid & 15, ty = tid >> 4;
    float acc[4][4] = {};
    for (int k0 = 0; k0 < K; k0 += BK) {
        for (int l = tid; l < BM * BK; l += 256) {
            int row = l >> 4, kk = l & 15;
            int gr = bm + row;
            Asm[kk][row] = (gr < M) ? A[(size_t)gr * K + k0 + kk] : 0.f;
        }
        for (int l = tid; l < BN * BK; l += 256) {
            int col = l >> 4, kk = l & 15;
            int gc = bn + col;
            Bsm[kk][col] = (gc < N) ? W[(size_t)gc * K + k0 + kk] : 0.f;
        }
        __syncthreads();
        #pragma unroll
        for (int kk = 0; kk < BK; ++kk) {
            float a0[4], b0[4];
            #pragma unroll
            for (int i = 0; i < 4; ++i) a0[i] = Asm[kk][ty * 4 + i];
            #pragma unroll
            for (int j = 0; j < 4; ++j) b0[j] = Bsm[kk][tx * 4 + j];
            #pragma unroll
            for (int i = 0; i < 4; ++i)
                #pragma unroll
                for (int j = 0; j < 4; ++j) acc[i][j] += a0[i] * b0[j];
        }
        __syncthreads();
    }
    #pragma unroll
    for (int i = 0; i < 4; ++i) {
        int gr = bm + ty * 4 + i;
        if (gr >= M) continue;
        #pragma unroll
        for (int j = 0; j < 4; ++j) {
            int gc = bn + tx * 4 + j;
            if (gc >= N) continue;
            C[(size_t)gr * N + gc] = acc[i][j] + (bias ? bias[gc] : 0.f);
        }
    }
}

// ---------------- MFMA attention: one block per (b, head, half) --------------
// K [208][72] bf16 LDS, V^T [64][232] bf16 LDS, per-wave P chunk [16][40].
// Per 16-query tile: S = Q@K^T (13x2 MFMAs), poly/softmax in C-layout regs,
// P -> LDS chunk -> A-frags -> O += P@V (7x4 MFMAs).
__global__ __launch_bounds__(256) void attn_k(const u16* __restrict__ qkv, u16* __restrict__ o,
                                              const float* __restrict__ alpha, const float* __restrict__ beta,
                                              const float* __restrict__ gamma, int layer, int poly) {
    __shared__ u16 Kb[208 * 72];
    __shared__ u16 Vt[64 * 232];
    __shared__ u16 Pb[4][16 * 40];
    const int tid = threadIdx.x, wv = tid >> 6, lane = tid & 63;
    const int l15 = lane & 15, quad = lane >> 4;
    const int id = blockIdx.x;
    const int half = id & 1, bh = id >> 1;
    const int hh = bh % NH, b = bh / NH;
    const u16* base = qkv + (size_t)b * NT * QKVD;
    // stage K rows (pad rows >=197 with 0) and V transposed (pad m in [197,224) with 0)
    for (int idx = tid; idx < 208 * 64; idx += 256) {
        int m = idx >> 6, d = idx & 63;
        Kb[m * 72 + d] = (m < NT) ? base[(size_t)m * QKVD + D_ + hh * 64 + d] : (u16)0;
    }
    for (int idx = tid; idx < 224 * 64; idx += 256) {
        int m = idx >> 6, d = idx & 63;
        Vt[d * 232 + m] = (m < NT) ? base[(size_t)m * QKVD + 2 * D_ + hh * 64 + d] : (u16)0;
    }
    __syncthreads();
    float pa = 0.f, pcb = 0.f, pg = 0.f;
    if (poly) { pa = alpha[layer * NH + hh]; pcb = beta[layer * NH + hh]; pg = gamma[layer * NH + hh]; }

    for (int qt = half + 2 * wv; qt < 13; qt += 8) {
        int qrow = qt * 16 + l15; if (qrow > NT - 1) qrow = NT - 1;
        const u16* qp = base + (size_t)qrow * QKVD + hh * 64;
        bf16x8 aq0 = *(const bf16x8*)(qp + quad * 8);
        bf16x8 aq1 = *(const bf16x8*)(qp + 32 + quad * 8);
        f32x4 S[13];
        #pragma unroll
        for (int f = 0; f < 13; ++f) {
            const u16* kp = Kb + (f * 16 + l15) * 72;
            bf16x8 b0 = *(const bf16x8*)(kp + quad * 8);
            bf16x8 b1 = *(const bf16x8*)(kp + 32 + quad * 8);
            f32x4 c = {};
            c = __builtin_amdgcn_mfma_f32_16x16x32_bf16(aq0, b0, c, 0, 0, 0);
            c = __builtin_amdgcn_mfma_f32_16x16x32_bf16(aq1, b1, c, 0, 0, 0);
            S[f] = c;
        }
        // --- normalize rows (row = quad*4+r across 16 lanes l15, 13 frags) ---
        float inv[4];
        if (poly) {
            float s[4] = {0.f, 0.f, 0.f, 0.f};
            #pragma unroll
            for (int f = 0; f < 13; ++f) {
                bool iv = (f == 12) && (l15 >= 5);
                #pragma unroll
                for (int r = 0; r < 4; ++r) {
                    float l = S[f][r] * 0.125f;
                    float p = fmaxf(pa * l * l + pcb * l + pg, 0.f);
                    if (iv) p = 0.f;
                    S[f][r] = p;
                    s[r] += p;
                }
            }
            #pragma unroll
            for (int off = 1; off < 16; off <<= 1)
                #pragma unroll
                for (int r = 0; r < 4; ++r) s[r] += __shfl_xor(s[r], off);
            #pragma unroll
            for (int r = 0; r < 4; ++r) inv[r] = 1.f / (s[r] + 1e-6f);
        } else {
            float mx[4] = {-1e30f, -1e30f, -1e30f, -1e30f};
            #pragma unroll
            for (int f = 0; f < 13; ++f) {
                bool iv = (f == 12) && (l15 >= 5);
                #pragma unroll
                for (int r = 0; r < 4; ++r) {
                    float l = iv ? -1e30f : S[f][r] * 0.125f;
                    S[f][r] = l;
                    mx[r] = fmaxf(mx[r], l);
                }
            }
            #pragma unroll
            for (int off = 1; off < 16; off <<= 1)
                #pragma unroll
                for (int r = 0; r < 4; ++r) mx[r] = fmaxf(mx[r], __shfl_xor(mx[r], off));
            float s[4] = {0.f, 0.f, 0.f, 0.f};
            #pragma unroll
            for (int f = 0; f < 13; ++f)
                #pragma unroll
                for (int r = 0; r < 4; ++r) {
                    float e = __expf(S[f][r] - mx[r]);
                    S[f][r] = e;
                    s[r] += e;
                }
            #pragma unroll
            for (int off = 1; off < 16; off <<= 1)
                #pragma unroll
                for (int r = 0; r < 4; ++r) s[r] += __shfl_xor(s[r], off);
            #pragma unroll
            for (int r = 0; r < 4; ++r) inv[r] = 1.f / s[r];
        }
        #pragma unroll
        for (int f = 0; f < 13; ++f)
            #pragma unroll
            for (int r = 0; r < 4; ++r) S[f][r] *= inv[r];
        // --- PV: per 32-wide m chunk, wave-local LDS roundtrip to A layout ---
        f32x4 O[4] = {};
        u16* pb = &Pb[wv][0];
        #pragma unroll
        for (int c = 0; c < 7; ++c) {
            int f0 = 2 * c, f1 = 2 * c + 1;
            __asm__ volatile("s_waitcnt lgkmcnt(0)" ::: "memory");   // WAR on prior chunk reads
            #pragma unroll
            for (int r = 0; r < 4; ++r) {
                pb[(quad * 4 + r) * 40 + l15]      = f2bf(S[f0][r]);
                pb[(quad * 4 + r) * 40 + 16 + l15] = (f1 < 13) ? f2bf(S[f1][r]) : (u16)0;
            }
            __asm__ volatile("s_waitcnt lgkmcnt(0)" ::: "memory");   // writes visible to own wave
            bf16x8 ap = *(const bf16x8*)(pb + l15 * 40 + quad * 8);
            #pragma unroll
            for (int dt = 0; dt < 4; ++dt) {
                bf16x8 bv = *(const bf16x8*)(Vt + (dt * 16 + l15) * 232 + c * 32 + quad * 8);
                O[dt] = __builtin_amdgcn_mfma_f32_16x16x32_bf16(ap, bv, O[dt], 0, 0, 0);
            }
        }
        #pragma unroll
        for (int dt = 0; dt < 4; ++dt)
            #pragma unroll
            for (int r = 0; r < 4; ++r) {
                int n = qt * 16 + quad * 4 + r;
                if (n < NT)
                    o[((size_t)b * NT + n) * D_ + hh * 64 + dt * 16 + l15] = f2bf(O[dt][r]);
            }
    }
}

// -----------------------------------------------------------------------------
extern "C" void kernel_launch(void* const* d_in, const int* in_sizes, int n_in,
                              void* d_out, int out_size, void* d_ws, size_t ws_size,
                              hipStream_t stream) {
    (void)in_sizes; (void)n_in; (void)out_size; (void)ws_size;
    const float* x        = (const float*)d_in[0];
    const float* patch_w  = (const float*)d_in[1];
    const float* patch_b  = (const float*)d_in[2];
    const float* cls_tok  = (const float*)d_in[3];
    const float* pos      = (const float*)d_in[4];
    const float* ln1_w    = (const float*)d_in[5];
    const float* ln1_b    = (const float*)d_in[6];
    const float* qkv_w    = (const float*)d_in[7];
    const float* proj_w   = (const float*)d_in[8];
    const float* proj_b   = (const float*)d_in[9];
    const float* ln2_w    = (const float*)d_in[10];
    const float* ln2_b    = (const float*)d_in[11];
    const float* mlp_w1   = (const float*)d_in[12];
    const float* mlp_b1   = (const float*)d_in[13];
    const float* mlp_w2   = (const float*)d_in[14];
    const float* mlp_b2   = (const float*)d_in[15];
    const float* alpha    = (const float*)d_in[16];
    const float* beta     = (const float*)d_in[17];
    const float* gamma    = (const float*)d_in[18];
    const float* norm_w   = (const float*)d_in[19];
    const float* norm_b   = (const float*)d_in[20];
    const float* head_w   = (const float*)d_in[21];
    const float* head_b   = (const float*)d_in[22];

    const int MASK[12] = {1,0,1,0,1,0,1,0,1,0,1,0};
    const size_t ROWS = (size_t)B_ * NT;   // 6304

    char* p = (char*)d_ws;
    float* h    = (float*)p;  p += ROWS * D_ * 4;          // 19.4 MB
    float* qkvb = (float*)p;  p += ROWS * QKVD * 4;        // 58.1 MB (tokemb fp32 / qkv bf16)
    u16*   abuf = (u16*)p;    p += ROWS * D_ * 2;          // 9.7 MB  (ln/attn outs)
    u16*   gbuf = (u16*)p;    p += ROWS * MLP_ * 2;        // 38.7 MB (gelu out; also tok)
    u16*   wbuf = (u16*)p;    p += (size_t)7077888 * 2;    // 14.2 MB (per-layer bf16 weights)
    float* hb   = (float*)p;  p += 32 * D_ * 4;
    u16*   qkvbf = (u16*)qkvb;

    u16* wq = wbuf;
    u16* wp = wq + 1769472;
    u16* w1 = wp + 589824;
    u16* w2 = w1 + 2359296;

    // ---- patch embedding (bf16 MFMA) ----
    cvt1_k<<<576, 256, 0, stream>>>(patch_w, wbuf, 589824);
    patchify_k<<<B_ * NP, 256, 0, stream>>>(x, gbuf);
    mgemm_k<0><<<dim3(D_ / 128, 49), 256, 0, stream>>>(gbuf, wbuf, patch_b, qkvb, nullptr,
                                                       B_ * NP, D_, D_);
    assemble_h_k<<<B_ * NT, 256, 0, stream>>>(qkvb, cls_tok, pos, h);

    // ---- transformer layers ----
    for (int i = 0; i < 12; ++i) {
        cvtw_k<<<6912, 256, 0, stream>>>(qkv_w + (size_t)i * 1769472, proj_w + (size_t)i * 589824,
                                         mlp_w1 + (size_t)i * 2359296, mlp_w2 + (size_t)i * 2359296, wbuf);
        ln_k<1><<<(int)ROWS, 256, 0, stream>>>(h, D_, ln1_w + (size_t)i * D_, ln1_b + (size_t)i * D_,
                                               nullptr, abuf);
        mgemm_k<3><<<dim3(QKVD / 128, 50), 256, 0, stream>>>(abuf, wq, nullptr, nullptr, qkvbf,
                                                             (int)ROWS, QKVD, D_);
        attn_k<<<B_ * NH * 2, 256, 0, stream>>>(qkvbf, abuf, alpha, beta, gamma, i, MASK[i]);
        mgemm_k<1><<<dim3(D_ / 128, 50), 256, 0, stream>>>(abuf, wp, proj_b + (size_t)i * D_, h, nullptr,
                                                           (int)ROWS, D_, D_);
        ln_k<1><<<(int)ROWS, 256, 0, stream>>>(h, D_, ln2_w + (size_t)i * D_, ln2_b + (size_t)i * D_,
                                               nullptr, abuf);
        mgemm_k<2><<<dim3(MLP_ / 128, 50), 256, 0, stream>>>(abuf, w1, mlp_b1 + (size_t)i * MLP_,
                                                             nullptr, gbuf, (int)ROWS, MLP_, D_);
        mgemm_k<1><<<dim3(D_ / 128, 50), 256, 0, stream>>>(gbuf, w2, mlp_b2 + (size_t)i * D_, h, nullptr,
                                                           (int)ROWS, D_, MLP_);
    }

    // ---- head: LN(cls rows) fp32, then [32,768] @ [1000,768]^T + bias -------
    ln_k<0><<<B_, 256, 0, stream>>>(h, (size_t)NT * D_, norm_w, norm_b, hb, nullptr);
    sgemm_k<<<dim3((NCLS + 63) / 64, 1), 256, 0, stream>>>(hb, head_w, head_b, (float*)d_out,
                                                           B_, NCLS, D_);
}

// Round 4
// 4992.258 us; speedup vs baseline: 7.9142x; 1.0833x over previous
//
#include <hip/hip_runtime.h>
#include <math.h>

#define B_    32
#define NT    197     // tokens (196 patches + cls)
#define NP    196
#define D_    768
#define NH    12
#define HD_   64
#define MLP_  3072
#define QKVD  2304
#define NCLS  1000

typedef unsigned short u16;
typedef __bf16 bf16x8 __attribute__((ext_vector_type(8)));
typedef float  f32x4  __attribute__((ext_vector_type(4)));
struct alignas(8) u16x4_t { u16 x, y, z, w; };

__device__ __forceinline__ u16 f2bf(float f) {
    unsigned u = __builtin_bit_cast(unsigned, f);
    u = u + 0x7FFFu + ((u >> 16) & 1u);
    return (u16)(u >> 16);
}
__device__ __forceinline__ void gload_lds16(const void* g, void* l) {
    __builtin_amdgcn_global_load_lds((const __attribute__((address_space(1))) unsigned*)g,
                                     (__attribute__((address_space(3))) unsigned*)l, 16, 0, 0);
}
// fast GELU (tanh form): abs err ~1e-3, far below the 0.047 threshold
__device__ __forceinline__ float gelu_f(float x) {
    float u = 0.7978845608f * (x + 0.044715f * x * x * x);
    u = fminf(fmaxf(u, -10.f), 10.f);
    float e = __expf(2.f * u);
    float t = (e - 1.f) * __builtin_amdgcn_rcpf(e + 1.f);
    return 0.5f * x * (1.f + t);
}

// ---------------- patchify: x[B,3,224,224] -> tok bf16 [B*196, 768] ----------
__global__ void patchify_k(const float* __restrict__ x, u16* __restrict__ tok) {
    int bp = blockIdx.x;
    int b = bp / NP, p = bp % NP;
    int ph = p / 14, pw = p % 14;
    const float* xb = x + (size_t)b * 3 * 224 * 224;
    u16* trow = tok + (size_t)bp * D_;
    for (int f = threadIdx.x; f < D_; f += blockDim.x) {
        int c = f >> 8;
        int r = f & 255;
        int i = r >> 4, j = r & 15;
        trow[f] = f2bf(xb[((size_t)c * 224 + (ph * 16 + i)) * 224 + (pw * 16 + j)]);
    }
}

// --------------- assemble h (fp32): cls+pos row0, tokemb+pos rows 1..196 -----
__global__ void assemble_h_k(const float* __restrict__ tokemb, const float* __restrict__ cls,
                             const float* __restrict__ pos, float* __restrict__ h) {
    int bn = blockIdx.x;
    int b = bn / NT, n = bn % NT;
    float* hr = h + (size_t)bn * D_;
    const float* pr = pos + (size_t)n * D_;
    if (n == 0) {
        for (int d = threadIdx.x; d < D_; d += blockDim.x) hr[d] = cls[d] + pr[d];
    } else {
        const float* tr = tokemb + ((size_t)b * NP + (n - 1)) * D_;
        for (int d = threadIdx.x; d < D_; d += blockDim.x) hr[d] = tr[d] + pr[d];
    }
}

// ---------------- fp32 -> bf16 weight conversion -----------------------------
__global__ void cvt1_k(const float* __restrict__ src, u16* __restrict__ dst, int n4) {
    int i = (blockIdx.x * 256 + threadIdx.x) * 4;
    if (i >= n4) return;
    float4 v = *(const float4*)(src + i);
    u16x4_t o; o.x = f2bf(v.x); o.y = f2bf(v.y); o.z = f2bf(v.z); o.w = f2bf(v.w);
    *(u16x4_t*)(dst + i) = o;
}

// fused per-layer weight conversion into wbuf [qkv | proj | mlp1 | mlp2]
__global__ void cvtw_k(const float* __restrict__ qw, const float* __restrict__ pw,
                       const float* __restrict__ m1, const float* __restrict__ m2,
                       u16* __restrict__ dst) {
    const size_t n0 = 1769472, n1 = 2359296, n2 = 4718592, n3 = 7077888;
    size_t e = ((size_t)blockIdx.x * 256 + threadIdx.x) * 4;
    if (e >= n3) return;
    const float* src; size_t off;
    if (e < n0)      { src = qw; off = e; }
    else if (e < n1) { src = pw; off = e - n0; }
    else if (e < n2) { src = m1; off = e - n1; }
    else             { src = m2; off = e - n2; }
    float4 v = *(const float4*)(src + off);
    u16x4_t o; o.x = f2bf(v.x); o.y = f2bf(v.y); o.z = f2bf(v.z); o.w = f2bf(v.w);
    *(u16x4_t*)(dst + e) = o;
}

// ---------------- LayerNorm over last dim (768), fp32 in, fp32/bf16 out ------
template<int OUTBF>
__global__ __launch_bounds__(256) void ln_k(const float* __restrict__ in, size_t in_row_stride,
                                            const float* __restrict__ w, const float* __restrict__ b,
                                            float* __restrict__ of, u16* __restrict__ ob) {
    int row = blockIdx.x;
    const float* xr = in + (size_t)row * in_row_stride;
    int tid = threadIdx.x;
    float s1 = 0.f, s2 = 0.f;
    for (int d = tid; d < D_; d += 256) { float v = xr[d]; s1 += v; s2 += v * v; }
    #pragma unroll
    for (int off = 32; off; off >>= 1) { s1 += __shfl_down(s1, off); s2 += __shfl_down(s2, off); }
    __shared__ float r1[4], r2[4];
    int wave = tid >> 6, lane = tid & 63;
    if (lane == 0) { r1[wave] = s1; r2[wave] = s2; }
    __syncthreads();
    float m1 = (r1[0] + r1[1] + r1[2] + r1[3]) * (1.0f / D_);
    float m2 = (r2[0] + r2[1] + r2[2] + r2[3]) * (1.0f / D_);
    float rs = rsqrtf(m2 - m1 * m1 + 1e-5f);
    for (int d = tid; d < D_; d += 256) {
        float y = (xr[d] - m1) * rs * w[d] + b[d];
        if (OUTBF) ob[(size_t)row * D_ + d] = f2bf(y);
        else       of[(size_t)row * D_ + d] = y;
    }
}

// ---------------- bf16 MFMA GEMM: C[M,N] = A[M,K] @ W[N,K]^T (+bias) ---------
// 128x128 tile, BK=64, 256 thr = 4 waves in 2x2, each wave 4x4 16x16x32 MFMAs.
// LDS is XOR-swizzled in 16B chunks: LDS[row][c] = G[row][c ^ (row&7)], which
// turns the 16-way bank conflict of the naive layout into conflict-free 2-way.
// EPI: 0 = store fp32, 1 = fp32 += (residual), 2 = GELU -> bf16, 3 = bf16 store
template<int EPI>
__global__ __launch_bounds__(256) void mgemm_k(const u16* __restrict__ A, const u16* __restrict__ W,
                                               const float* __restrict__ bias, float* __restrict__ Cf,
                                               u16* __restrict__ Cb, int M, int N, int K) {
    __shared__ u16 As[128 * 64];
    __shared__ u16 Ws[128 * 64];
    const int tid = threadIdx.x;
    const int lane = tid & 63, wv = tid >> 6;
    const int wr = wv >> 1, wc = wv & 1;
    const int bm = blockIdx.y * 128, bn = blockIdx.x * 128;
    const int rloc = tid >> 3;                     // 0..31 (LDS row within 32-row chunk)
    const int cs8 = ((tid & 7) ^ (rloc & 7)) * 8;  // swizzled src column (elements)
    const int l15 = lane & 15, quad = lane >> 4;
    const int sw = l15 & 7;                        // read-side swizzle key
    f32x4 acc[4][4] = {};
    for (int k0 = 0; k0 < K; k0 += 64) {
        #pragma unroll
        for (int q = 0; q < 4; ++q) {
            int gr = bm + q * 32 + rloc;
            if (gr > M - 1) gr = M - 1;                       // clamp edge tile
            gload_lds16(A + (size_t)gr * K + k0 + cs8, (char*)As + q * 4096 + tid * 16);
        }
        #pragma unroll
        for (int q = 0; q < 4; ++q) {
            int r = q * 32 + rloc;                            // N is always a multiple of 128
            gload_lds16(W + (size_t)(bn + r) * K + k0 + cs8, (char*)Ws + q * 4096 + tid * 16);
        }
        __syncthreads();
        #pragma unroll
        for (int kk = 0; kk < 64; kk += 32) {
            const int kc = (kk >> 3) + quad;                  // 16B chunk index pre-swizzle
            const int co = ((kc ^ sw) * 8);                   // swizzled element offset
            bf16x8 af[4], bfr[4];
            #pragma unroll
            for (int i = 0; i < 4; ++i)
                af[i] = *(const bf16x8*)(As + (wr * 64 + i * 16 + l15) * 64 + co);
            #pragma unroll
            for (int j = 0; j < 4; ++j)
                bfr[j] = *(const bf16x8*)(Ws + (wc * 64 + j * 16 + l15) * 64 + co);
            #pragma unroll
            for (int i = 0; i < 4; ++i)
                #pragma unroll
                for (int j = 0; j < 4; ++j)
                    acc[i][j] = __builtin_amdgcn_mfma_f32_16x16x32_bf16(af[i], bfr[j], acc[i][j], 0, 0, 0);
        }
        __syncthreads();
    }
    #pragma unroll
    for (int i = 0; i < 4; ++i) {
        int rb = bm + wr * 64 + i * 16 + quad * 4;            // C/D: col=lane&15, row=quad*4+reg
        #pragma unroll
        for (int j = 0; j < 4; ++j) {
            int gc = bn + wc * 64 + j * 16 + l15;
            #pragma unroll
            for (int r = 0; r < 4; ++r) {
                int gr = rb + r;
                if (gr >= M) continue;
                float v = acc[i][j][r];
                if (bias) v += bias[gc];
                size_t idx = (size_t)gr * N + gc;
                if (EPI == 0)      Cf[idx] = v;
                else if (EPI == 1) Cf[idx] += v;
                else if (EPI == 3) Cb[idx] = f2bf(v);
                else Cb[idx] = f2bf(gelu_f(v));
            }
        }
    }
}

// ---------------- fp32 GEMM (head only): C[M,N] = A@W^T + bias ---------------
__global__ __launch_bounds__(256) void sgemm_k(const float* __restrict__ A, const float* __restrict__ W,
                                               const float* __restrict__ bias, float* __restrict__ C,
                                               int M, int N, int K) {
    const int BM = 64, BN = 64, BK = 16;
    __shared__ float Asm[BK][BM + 1];
    __shared__ float Bsm[BK][BN + 1];
    int bm = blockIdx.y * BM, bn = blockIdx.x * BN;
    int tid = threadIdx.x;
    int tx = tid & 15, ty = tid >> 4;
    float acc[4][4] = {};
    for (int k0 = 0; k0 < K; k0 += BK) {
        for (int l = tid; l < BM * BK; l += 256) {
            int row = l >> 4, kk = l & 15;
            int gr = bm + row;
            Asm[kk][row] = (gr < M) ? A[(size_t)gr * K + k0 + kk] : 0.f;
        }
        for (int l = tid; l < BN * BK; l += 256) {
            int col = l >> 4, kk = l & 15;
            int gc = bn + col;
            Bsm[kk][col] = (gc < N) ? W[(size_t)gc * K + k0 + kk] : 0.f;
        }
        __syncthreads();
        #pragma unroll
        for (int kk = 0; kk < BK; ++kk) {
            float a0[4], b0[4];
            #pragma unroll
            for (int i = 0; i < 4; ++i) a0[i] = Asm[kk][ty * 4 + i];
            #pragma unroll
            for (int j = 0; j < 4; ++j) b0[j] = Bsm[kk][tx * 4 + j];
            #pragma unroll
            for (int i = 0; i < 4; ++i)
                #pragma unroll
                for (int j = 0; j < 4; ++j) acc[i][j] += a0[i] * b0[j];
        }
        __syncthreads();
    }
    #pragma unroll
    for (int i = 0; i < 4; ++i) {
        int gr = bm + ty * 4 + i;
        if (gr >= M) continue;
        #pragma unroll
        for (int j = 0; j < 4; ++j) {
            int gc = bn + tx * 4 + j;
            if (gc >= N) continue;
            C[(size_t)gr * N + gc] = acc[i][j] + (bias ? bias[gc] : 0.f);
        }
    }
}

// ---------------- MFMA attention: one block per (b, head, half) --------------
// K [208][72] bf16 LDS, V^T [64][232] bf16 LDS, per-wave P chunk [16][40].
__global__ __launch_bounds__(256) void attn_k(const u16* __restrict__ qkv, u16* __restrict__ o,
                                              const float* __restrict__ alpha, const float* __restrict__ beta,
                                              const float* __restrict__ gamma, int layer, int poly) {
    __shared__ u16 Kb[208 * 72];
    __shared__ u16 Vt[64 * 232];
    __shared__ u16 Pb[4][16 * 40];
    const int tid = threadIdx.x, wv = tid >> 6, lane = tid & 63;
    const int l15 = lane & 15, quad = lane >> 4;
    const int id = blockIdx.x;
    const int half = id & 1, bh = id >> 1;
    const int hh = bh % NH, b = bh / NH;
    const u16* base = qkv + (size_t)b * NT * QKVD;
    for (int idx = tid; idx < 208 * 64; idx += 256) {
        int m = idx >> 6, d = idx & 63;
        Kb[m * 72 + d] = (m < NT) ? base[(size_t)m * QKVD + D_ + hh * 64 + d] : (u16)0;
    }
    for (int idx = tid; idx < 224 * 64; idx += 256) {
        int m = idx >> 6, d = idx & 63;
        Vt[d * 232 + m] = (m < NT) ? base[(size_t)m * QKVD + 2 * D_ + hh * 64 + d] : (u16)0;
    }
    __syncthreads();
    float pa = 0.f, pcb = 0.f, pg = 0.f;
    if (poly) { pa = alpha[layer * NH + hh]; pcb = beta[layer * NH + hh]; pg = gamma[layer * NH + hh]; }

    for (int qt = half + 2 * wv; qt < 13; qt += 8) {
        int qrow = qt * 16 + l15; if (qrow > NT - 1) qrow = NT - 1;
        const u16* qp = base + (size_t)qrow * QKVD + hh * 64;
        bf16x8 aq0 = *(const bf16x8*)(qp + quad * 8);
        bf16x8 aq1 = *(const bf16x8*)(qp + 32 + quad * 8);
        f32x4 S[13];
        #pragma unroll
        for (int f = 0; f < 13; ++f) {
            const u16* kp = Kb + (f * 16 + l15) * 72;
            bf16x8 b0 = *(const bf16x8*)(kp + quad * 8);
            bf16x8 b1 = *(const bf16x8*)(kp + 32 + quad * 8);
            f32x4 c = {};
            c = __builtin_amdgcn_mfma_f32_16x16x32_bf16(aq0, b0, c, 0, 0, 0);
            c = __builtin_amdgcn_mfma_f32_16x16x32_bf16(aq1, b1, c, 0, 0, 0);
            S[f] = c;
        }
        float inv[4];
        if (poly) {
            float s[4] = {0.f, 0.f, 0.f, 0.f};
            #pragma unroll
            for (int f = 0; f < 13; ++f) {
                bool iv = (f == 12) && (l15 >= 5);
                #pragma unroll
                for (int r = 0; r < 4; ++r) {
                    float l = S[f][r] * 0.125f;
                    float p = fmaxf(pa * l * l + pcb * l + pg, 0.f);
                    if (iv) p = 0.f;
                    S[f][r] = p;
                    s[r] += p;
                }
            }
            #pragma unroll
            for (int off = 1; off < 16; off <<= 1)
                #pragma unroll
                for (int r = 0; r < 4; ++r) s[r] += __shfl_xor(s[r], off);
            #pragma unroll
            for (int r = 0; r < 4; ++r) inv[r] = 1.f / (s[r] + 1e-6f);
        } else {
            float mx[4] = {-1e30f, -1e30f, -1e30f, -1e30f};
            #pragma unroll
            for (int f = 0; f < 13; ++f) {
                bool iv = (f == 12) && (l15 >= 5);
                #pragma unroll
                for (int r = 0; r < 4; ++r) {
                    float l = iv ? -1e30f : S[f][r] * 0.125f;
                    S[f][r] = l;
                    mx[r] = fmaxf(mx[r], l);
                }
            }
            #pragma unroll
            for (int off = 1; off < 16; off <<= 1)
                #pragma unroll
                for (int r = 0; r < 4; ++r) mx[r] = fmaxf(mx[r], __shfl_xor(mx[r], off));
            float s[4] = {0.f, 0.f, 0.f, 0.f};
            #pragma unroll
            for (int f = 0; f < 13; ++f)
                #pragma unroll
                for (int r = 0; r < 4; ++r) {
                    float e = __expf(S[f][r] - mx[r]);
                    S[f][r] = e;
                    s[r] += e;
                }
            #pragma unroll
            for (int off = 1; off < 16; off <<= 1)
                #pragma unroll
                for (int r = 0; r < 4; ++r) s[r] += __shfl_xor(s[r], off);
            #pragma unroll
            for (int r = 0; r < 4; ++r) inv[r] = 1.f / s[r];
        }
        #pragma unroll
        for (int f = 0; f < 13; ++f)
            #pragma unroll
            for (int r = 0; r < 4; ++r) S[f][r] *= inv[r];
        f32x4 O[4] = {};
        u16* pb = &Pb[wv][0];
        #pragma unroll
        for (int c = 0; c < 7; ++c) {
            int f0 = 2 * c, f1 = 2 * c + 1;
            __asm__ volatile("s_waitcnt lgkmcnt(0)" ::: "memory");
            #pragma unroll
            for (int r = 0; r < 4; ++r) {
                pb[(quad * 4 + r) * 40 + l15]      = f2bf(S[f0][r]);
                pb[(quad * 4 + r) * 40 + 16 + l15] = (f1 < 13) ? f2bf(S[f1][r]) : (u16)0;
            }
            __asm__ volatile("s_waitcnt lgkmcnt(0)" ::: "memory");
            bf16x8 ap = *(const bf16x8*)(pb + l15 * 40 + quad * 8);
            #pragma unroll
            for (int dt = 0; dt < 4; ++dt) {
                bf16x8 bv = *(const bf16x8*)(Vt + (dt * 16 + l15) * 232 + c * 32 + quad * 8);
                O[dt] = __builtin_amdgcn_mfma_f32_16x16x32_bf16(ap, bv, O[dt], 0, 0, 0);
            }
        }
        #pragma unroll
        for (int dt = 0; dt < 4; ++dt)
            #pragma unroll
            for (int r = 0; r < 4; ++r) {
                int n = qt * 16 + quad * 4 + r;
                if (n < NT)
                    o[((size_t)b * NT + n) * D_ + hh * 64 + dt * 16 + l15] = f2bf(O[dt][r]);
            }
    }
}

// -----------------------------------------------------------------------------
extern "C" void kernel_launch(void* const* d_in, const int* in_sizes, int n_in,
                              void* d_out, int out_size, void* d_ws, size_t ws_size,
                              hipStream_t stream) {
    (void)in_sizes; (void)n_in; (void)out_size; (void)ws_size;
    const float* x        = (const float*)d_in[0];
    const float* patch_w  = (const float*)d_in[1];
    const float* patch_b  = (const float*)d_in[2];
    const float* cls_tok  = (const float*)d_in[3];
    const float* pos      = (const float*)d_in[4];
    const float* ln1_w    = (const float*)d_in[5];
    const float* ln1_b    = (const float*)d_in[6];
    const float* qkv_w    = (const float*)d_in[7];
    const float* proj_w   = (const float*)d_in[8];
    const float* proj_b   = (const float*)d_in[9];
    const float* ln2_w    = (const float*)d_in[10];
    const float* ln2_b    = (const float*)d_in[11];
    const float* mlp_w1   = (const float*)d_in[12];
    const float* mlp_b1   = (const float*)d_in[13];
    const float* mlp_w2   = (const float*)d_in[14];
    const float* mlp_b2   = (const float*)d_in[15];
    const float* alpha    = (const float*)d_in[16];
    const float* beta     = (const float*)d_in[17];
    const float* gamma    = (const float*)d_in[18];
    const float* norm_w   = (const float*)d_in[19];
    const float* norm_b   = (const float*)d_in[20];
    const float* head_w   = (const float*)d_in[21];
    const float* head_b   = (const float*)d_in[22];

    const int MASK[12] = {1,0,1,0,1,0,1,0,1,0,1,0};
    const size_t ROWS = (size_t)B_ * NT;   // 6304

    char* p = (char*)d_ws;
    float* h    = (float*)p;  p += ROWS * D_ * 4;          // 19.4 MB
    float* qkvb = (float*)p;  p += ROWS * QKVD * 4;        // 58.1 MB (tokemb fp32 / qkv bf16)
    u16*   abuf = (u16*)p;    p += ROWS * D_ * 2;          // 9.7 MB  (ln/attn outs)
    u16*   gbuf = (u16*)p;    p += ROWS * MLP_ * 2;        // 38.7 MB (gelu out; also tok)
    u16*   wbuf = (u16*)p;    p += (size_t)7077888 * 2;    // 14.2 MB (per-layer bf16 weights)
    float* hb   = (float*)p;  p += 32 * D_ * 4;
    u16*   qkvbf = (u16*)qkvb;

    u16* wq = wbuf;
    u16* wp = wq + 1769472;
    u16* w1 = wp + 589824;
    u16* w2 = w1 + 2359296;

    // ---- patch embedding (bf16 MFMA) ----
    cvt1_k<<<576, 256, 0, stream>>>(patch_w, wbuf, 589824);
    patchify_k<<<B_ * NP, 256, 0, stream>>>(x, gbuf);
    mgemm_k<0><<<dim3(D_ / 128, 49), 256, 0, stream>>>(gbuf, wbuf, patch_b, qkvb, nullptr,
                                                       B_ * NP, D_, D_);
    assemble_h_k<<<B_ * NT, 256, 0, stream>>>(qkvb, cls_tok, pos, h);

    // ---- transformer layers ----
    for (int i = 0; i < 12; ++i) {
        cvtw_k<<<6912, 256, 0, stream>>>(qkv_w + (size_t)i * 1769472, proj_w + (size_t)i * 589824,
                                         mlp_w1 + (size_t)i * 2359296, mlp_w2 + (size_t)i * 2359296, wbuf);
        ln_k<1><<<(int)ROWS, 256, 0, stream>>>(h, D_, ln1_w + (size_t)i * D_, ln1_b + (size_t)i * D_,
                                               nullptr, abuf);
        mgemm_k<3><<<dim3(QKVD / 128, 50), 256, 0, stream>>>(abuf, wq, nullptr, nullptr, qkvbf,
                                                             (int)ROWS, QKVD, D_);
        attn_k<<<B_ * NH * 2, 256, 0, stream>>>(qkvbf, abuf, alpha, beta, gamma, i, MASK[i]);
        mgemm_k<1><<<dim3(D_ / 128, 50), 256, 0, stream>>>(abuf, wp, proj_b + (size_t)i * D_, h, nullptr,
                                                           (int)ROWS, D_, D_);
        ln_k<1><<<(int)ROWS, 256, 0, stream>>>(h, D_, ln2_w + (size_t)i * D_, ln2_b + (size_t)i * D_,
                                               nullptr, abuf);
        mgemm_k<2><<<dim3(MLP_ / 128, 50), 256, 0, stream>>>(abuf, w1, mlp_b1 + (size_t)i * MLP_,
                                                             nullptr, gbuf, (int)ROWS, MLP_, D_);
        mgemm_k<1><<<dim3(D_ / 128, 50), 256, 0, stream>>>(gbuf, w2, mlp_b2 + (size_t)i * D_, h, nullptr,
                                                           (int)ROWS, D_, MLP_);
    }

    // ---- head: LN(cls rows) fp32, then [32,768] @ [1000,768]^T + bias -------
    ln_k<0><<<B_, 256, 0, stream>>>(h, (size_t)NT * D_, norm_w, norm_b, hb, nullptr);
    sgemm_k<<<dim3((NCLS + 63) / 64, 1), 256, 0, stream>>>(hb, head_w, head_b, (float*)d_out,
                                                           B_, NCLS, D_);
}